// Round 7
// baseline (604.785 us; speedup 1.0000x reference)
//
#include <hip/hip_runtime.h>
#include <math.h>

#define PI2f 6.28318530717958647692f

// B=16, Ci=Co=64, H=W=256, M1=M2=16. Modes j=0..31, freq f=(j<16)?j:j-32.
//
// ALL scratch lives inside d_out (67,108,864 floats = 1024 regions x 65536).
// Region-relative float offsets:
//   Ft slice bo : [0, 1024)      (mix_k -> inv_fused; 512 modes complex)
//   X  slice bi : [2048, 3072)   (fwdH -> mix_k; 512 modes complex)
//   A  slice bi : [8192, 16384)  (fwdW -> fwdH; layout [k][h] complex)
//   Wc chunk    : [16384, 20480) (wcat -> mix_k; Wc[i][o][m] complex, linear
//                                 float idx d lives at region d>>12, off 16384+(d&4095))
//   tw table    : region 0 [32768, 40960)  (twinit -> fwdW)
// inv_fused block bo stages its own Ft to LDS BEFORE overwriting its region.

static constexpr size_t REG = 65536;
static constexpr size_t TW_ABS = 32768;

// ---------------- twiddle table: tw[w*16+k] = e^{-2pi i wk/256} ----------------
__global__ __launch_bounds__(256) void twinit(float* __restrict__ g) {
    int idx = blockIdx.x * 256 + threadIdx.x;   // 0..4095
    int w = idx >> 4, k = idx & 15;
    int r = (w * k) & 255;                      // exact arg reduction
    float s, c;
    sincosf(PI2f * (float)r / 256.0f, &s, &c);
    g[TW_ABS + (size_t)idx * 2]     = c;
    g[TW_ABS + (size_t)idx * 2 + 1] = -s;
}

// ---------------- weights concat: Wc[i][o][m], coalesced both sides ----------------
// float4 units: w1/w2 each 524288 float4. grid MUST be 2048 blocks.
__global__ __launch_bounds__(256) void wcat(const float4* __restrict__ w1,
                                            const float4* __restrict__ w2,
                                            float4* __restrict__ g4) {
    int tid = blockIdx.x * 256 + threadIdx.x;   // 0..524287 (float4 units)
    int io = tid >> 7, rem = tid & 127;
    float4 a = w1[tid];
    float4 b = w2[tid];
    int d1 = io * 256 + rem;                    // Wc float4 idx, m<256 half
    int d2 = d1 + 128;                          // m>=256 half
    g4[(size_t)(d1 >> 10) * 16384 + 4096 + (d1 & 1023)] = a;
    g4[(size_t)(d2 >> 10) * 16384 + 4096 + (d2 & 1023)] = b;
}

// ---------------- stage 1: A[k][h] = sum_w x[h][w] e^{-2pi i k w/256} ----------------
// grid 2048: block = 128 rows of one image. 2 threads per row (w-halves u=0/1),
// 8 chunks x 32 cols, register prefetch of next chunk, twiddles via scalar pipe.
__global__ __launch_bounds__(256, 6) void fwdW(const float* __restrict__ x,
                                               const float* __restrict__ twg,
                                               float* __restrict__ g) {
    __shared__ float xs[128 * 33];              // 16.9 KB
    const int t = threadIdx.x;
    const int bi = blockIdx.x >> 1, bh = blockIdx.x & 1;
    const float* xim = x + (size_t)bi * 65536 + (size_t)bh * 128 * 256;
    const int r = t & 127, u = t >> 7;          // row-in-tile, col-half (wave-uniform)

    float ar[16], ai[16];
#pragma unroll
    for (int k = 0; k < 16; k++) { ar[k] = 0.f; ai[k] = 0.f; }

    // staging map: idx = q*256+t -> row = idx>>3, c4 = (idx&7)*4 (128B/row segments)
    float4 pf[4];
#pragma unroll
    for (int q = 0; q < 4; q++) {
        int idx = q * 256 + t, rr = idx >> 3, c4 = (idx & 7) * 4;
        pf[q] = *(const float4*)(xim + (size_t)rr * 256 + c4);
    }
    for (int cc = 0; cc < 8; cc++) {
        __syncthreads();                        // prev chunk's reads done
#pragma unroll
        for (int q = 0; q < 4; q++) {
            int idx = q * 256 + t, rr = idx >> 3, c4 = (idx & 7) * 4;
            float* d = xs + rr * 33 + c4;
            d[0] = pf[q].x; d[1] = pf[q].y; d[2] = pf[q].z; d[3] = pf[q].w;
        }
        __syncthreads();
        if (cc < 7) {                           // prefetch next chunk into regs
#pragma unroll
            for (int q = 0; q < 4; q++) {
                int idx = q * 256 + t, rr = idx >> 3, c4 = (idx & 7) * 4;
                pf[q] = *(const float4*)(xim + (size_t)rr * 256 + (cc + 1) * 32 + c4);
            }
        }
        const float* xr = xs + r * 33 + u * 16;
        const int w0 = cc * 32 + u * 16;
#pragma unroll
        for (int w = 0; w < 16; w++) {
            float xv = xr[w];
            const float* tp = twg + (w0 + w) * 32;      // wave-uniform -> scalar pipe
#pragma unroll
            for (int k = 0; k < 16; k++) {
                ar[k] = fmaf(xv, tp[2 * k],     ar[k]);
                ai[k] = fmaf(xv, tp[2 * k + 1], ai[k]);
            }
        }
    }
    // pairwise reduce the two w-halves through LDS (pitch 33 -> spread banks)
    __syncthreads();
    if (u == 1) {
        float* p = xs + r * 33;
#pragma unroll
        for (int k = 0; k < 16; k++) { p[2 * k] = ar[k]; p[2 * k + 1] = ai[k]; }
    }
    __syncthreads();
    if (u == 0) {
        const float* p = xs + r * 33;
        float* Ap = g + (size_t)bi * REG + 8192;
#pragma unroll
        for (int k = 0; k < 16; k++) {
            float vr = ar[k] + p[2 * k];
            float vi = ai[k] + p[2 * k + 1];
            *(float2*)(Ap + ((size_t)k * 256 + bh * 128 + r) * 2) = make_float2(vr, vi);
        }
    }
}

// ---------------- stage 2: X[j][k] = sum_h A[k][h] e^{-2pi i f(j) h/256} ----------------
// 512 threads: one mode per thread (k = t&15, j = t>>4).
__global__ __launch_bounds__(512, 8) void fwdH(float* __restrict__ g) {
    __shared__ float As[16 * 516 + 4];          // [k][h] pad-2 complex, 33 KB
    const int bi = blockIdx.x, t = threadIdx.x;
    const float* Ap = g + (size_t)bi * REG + 8192;
#pragma unroll
    for (int q = 0; q < 4; q++) {
        int f4 = q * 512 + t;                   // float4 id 0..2047
        int k = f4 >> 7, r4 = f4 & 127;
        *(float4*)(As + k * 516 + r4 * 4) = *(const float4*)(Ap + (size_t)f4 * 4);
    }
    __syncthreads();

    const int k = t & 15, j = t >> 4;
    const float* Ak = As + k * 516;
    const int f = (j < 16) ? j : j - 32;
    float s, c;
    sincosf(-PI2f * (float)f / 256.0f, &s, &c);
    float er = 1.f, ei = 0.f, accr = 0.f, acci = 0.f;
    for (int h = 0; h < 256; h++) {
        float a_re = Ak[2 * h], a_im = Ak[2 * h + 1];
        accr = fmaf(a_re, er, fmaf(-a_im, ei, accr));
        acci = fmaf(a_re, ei, fmaf( a_im, er, acci));
        float nr = er * c - ei * s;
        ei = fmaf(er, s, ei * c);
        er = nr;
    }
    float* Xp = g + (size_t)bi * REG + 2048;
    *(float2*)(Xp + ((size_t)j * 16 + k) * 2) = make_float2(accr, acci);
}

// ---------------- stage 3: Ft[b][m][o] = sum_i X[b][i][m] * Wc[i][o][m] ----------------
// wave = (b, o, quarter): lane owns m = qr*128 + l*2 + {0,1}; all loads/stores float4-coalesced
__global__ __launch_bounds__(256) void mix_k(float* __restrict__ g) {
    const int wv = threadIdx.x >> 6, l = threadIdx.x & 63;
    const int W = blockIdx.x * 4 + wv;          // 0..4095
    const int b = W >> 8, o = (W >> 2) & 63, qr = W & 3;
    float acr0 = 0.f, aci0 = 0.f, acr1 = 0.f, aci1 = 0.f;
    for (int i = 0; i < 64; i++) {
        const float4 xv = *(const float4*)(g + (size_t)(b * 64 + i) * REG + 2048 + qr * 256 + l * 4);
        int d0 = (i * 64 + o) * 1024 + qr * 256;    // Wc float idx base
        const float4 wv4 = *(const float4*)(g + (size_t)(d0 >> 12) * REG + 16384 + (d0 & 4095) + l * 4);
        acr0 = fmaf(xv.x, wv4.x, fmaf(-xv.y, wv4.y, acr0));
        aci0 = fmaf(xv.x, wv4.y, fmaf( xv.y, wv4.x, aci0));
        acr1 = fmaf(xv.z, wv4.z, fmaf(-xv.w, wv4.w, acr1));
        aci1 = fmaf(xv.z, wv4.w, fmaf( xv.w, wv4.z, aci1));
    }
    float* Fp = g + (size_t)(b * 64 + o) * REG + qr * 256 + l * 4;
    *(float4*)Fp = make_float4(acr0, aci0, acr1, aci1);
}

// ---------------- inverse: H-iDFT + irfft-W, full-sector coalesced stores ----------------
// block = one bo region. Thread t owns output row h=t.
// Phase 2: 8 chunks x 32 cols (16 lo + 16 mirrored hi, hi stored reversed so it
// is column-ascending). Transpose via 32KB XOR-swizzled LDS tile; float4 stores
// in 64B-aligned segments -> no partial-sector RMW at HBM.
__global__ __launch_bounds__(256, 4) void inv_fused(float* __restrict__ g) {
    __shared__ float Fs[1024];                  // Ft slice, 4 KB
    __shared__ float phS[512];                  // cos/sin(2pi m/256), 2 KB
    __shared__ float T[256 * 32];               // swizzled transpose tile, 32 KB
    const int t = threadIdx.x;
    const int bo = blockIdx.x;
    float* regn = g + (size_t)bo * REG;

    // stage own Ft slice BEFORE any output write
    *(float4*)(Fs + t * 4) = *(const float4*)(regn + (size_t)t * 4);
    float rs, rc;
    sincosf(PI2f * (float)t / 256.0f, &rs, &rc);
    phS[t * 2] = rc; phS[t * 2 + 1] = rs;
    __syncthreads();

    // phase 1: Y[h=t][k] = sum_f Ft[j(f)][k] e^{+2pi i f t/256}, f=-16..15
    float Yr[16], Yi[16];
#pragma unroll
    for (int k = 0; k < 16; k++) { Yr[k] = 0.f; Yi[k] = 0.f; }
    float es, ec;
    sincosf(-PI2f * (float)(t & 15) / 16.0f, &es, &ec); // e^{-2pi i 16 t/256}
    float er = ec, ei = es;
    for (int sdx = 0; sdx < 32; sdx++) {                // f = sdx-16
        int j = (sdx < 16) ? sdx + 16 : sdx - 16;
        const float* fj = Fs + j * 32;
#pragma unroll
        for (int k = 0; k < 16; k++) {
            float fr = fj[2 * k], fi = fj[2 * k + 1];
            Yr[k] = fmaf(fr, er, fmaf(-fi, ei, Yr[k]));
            Yi[k] = fmaf(fr, ei, fmaf( fi, er, Yi[k]));
        }
        float nr = er * rc - ei * rs;
        ei = fmaf(er, rs, ei * rc);
        er = nr;
    }

    // fold irfft weights (k=0: 1, k>=1: 2) and 1/65536
    const float INV = 1.0f / 65536.0f;
    Yr[0] *= INV;
#pragma unroll
    for (int k = 1; k < 16; k++) { Yr[k] *= 2.0f * INV; Yi[k] *= 2.0f * INV; }

    // P(m) = sum_k Yr[k] cos(2pi mk/256), Q(m) = sum_k Yi[k] sin(.)
    auto pq = [&](float c, float s, float& P, float& Q) {
        float c2 = c + c;
        float Cp = c, Cpp = 1.f, Sp = s, Spp = 0.f;
        P = fmaf(Yr[1], c, Yr[0]);
        Q = Yi[1] * s;
#pragma unroll
        for (int k = 2; k < 16; k++) {          // Chebyshev 3-term
            float Cn = fmaf(c2, Cp, -Cpp);
            float Sn = fmaf(c2, Sp, -Spp);
            P = fmaf(Yr[k], Cn, P);
            Q = fmaf(Yi[k], Sn, Q);
            Cpp = Cp; Cp = Cn; Spp = Sp; Sp = Sn;
        }
    };

    // phase 2: per chunk cc, cols lo = [cc*16, cc*16+16) and hi = mirrors
    const int sw = t & 7;                       // swizzle key for own row
    for (int cc = 0; cc < 8; cc++) {
        float lo[16], hi[16];
#pragma unroll
        for (int i = 0; i < 16; i++) {
            int m = cc * 16 + i;
            float P, Q;
            pq(phS[2 * m], phS[2 * m + 1], P, Q);
            lo[i] = P - Q;                      // col m
            hi[i] = P + Q;                      // col 256-m
        }
        if (cc == 0) {                          // m=0 has no mirror; slot carries col 128
            float P, Q;
            pq(-1.0f, 0.0f, P, Q);              // c=-1, s=0 -> Q=0
            hi[0] = P;
        }
        __syncthreads();                        // prev chunk's T reads done
        // T[t][c]: c<16 -> lo[c]; c=16+p -> hi[15-p] (reversed -> ascending cols)
        float* Tr = T + t * 32;
#pragma unroll
        for (int q = 0; q < 4; q++) {
            *(float4*)(Tr + ((q ^ sw) * 4)) =
                make_float4(lo[q * 4], lo[q * 4 + 1], lo[q * 4 + 2], lo[q * 4 + 3]);
        }
#pragma unroll
        for (int q = 0; q < 4; q++) {
            *(float4*)(Tr + (((4 + q) ^ sw) * 4)) =
                make_float4(hi[15 - q * 4], hi[14 - q * 4], hi[13 - q * 4], hi[12 - q * 4]);
        }
        __syncthreads();
        // store-out: row = it*32 + (t>>3), f4 = t&7; 64B segments, float4
        const int rsub = t >> 3, f4 = t & 7;
#pragma unroll
        for (int it = 0; it < 8; it++) {
            int row = it * 32 + rsub;
            float4 v = *(const float4*)(T + row * 32 + ((f4 ^ (row & 7)) * 4));
            if (f4 < 4) {                       // lo block: cols cc*16 + f4*4 ..+3
                *(float4*)(regn + (size_t)row * 256 + cc * 16 + f4 * 4) = v;
            } else {
                int jq = f4 - 4;                // hi block: cols (241-cc*16)+jq*4 ..+3
                if (cc == 0 && jq == 3) {       // cols 253,254,255,128
                    float* rp = regn + (size_t)row * 256;
                    rp[253] = v.x; rp[254] = v.y; rp[255] = v.z; rp[128] = v.w;
                } else {
                    *(float4*)(regn + (size_t)row * 256 + (241 - cc * 16) + jq * 4) = v;
                }
            }
        }
    }
}

extern "C" void kernel_launch(void* const* d_in, const int* in_sizes, int n_in,
                              void* d_out, int out_size, void* d_ws, size_t ws_size,
                              hipStream_t stream) {
    const float* x  = (const float*)d_in[0];
    const float* w1 = (const float*)d_in[1];
    const float* w2 = (const float*)d_in[2];
    float* g = (float*)d_out;
    (void)d_ws; (void)ws_size;

    twinit   <<<16,   256, 0, stream>>>(g);
    wcat     <<<2048, 256, 0, stream>>>((const float4*)w1, (const float4*)w2, (float4*)g);
    fwdW     <<<2048, 256, 0, stream>>>(x, g + TW_ABS, g);
    fwdH     <<<1024, 512, 0, stream>>>(g);
    mix_k    <<<1024, 256, 0, stream>>>(g);
    inv_fused<<<1024, 256, 0, stream>>>(g);
}

// Round 8
// 285.857 us; speedup vs baseline: 2.1157x; 2.1157x over previous
//
#include <hip/hip_runtime.h>
#include <math.h>

#define PI2f 6.28318530717958647692f

// B=16, Ci=Co=64, H=W=256, M1=M2=16. Modes j=0..31, freq f=(j<16)?j:j-32.
//
// ALL scratch lives inside d_out (67,108,864 floats = 1024 regions x 65536).
// Region-relative float offsets:
//   Ft slice bo : [0, 1024)      (mix_k -> inv_fused; 512 modes complex)
//   X  slice bi : [2048, 3072)   (fwdH -> mix_k; 512 modes complex)
//   A  slice bi : [8192, 16384)  (fwdW -> fwdH; layout [k][h] complex)
//   Wc chunk    : [16384, 20480) (wcat -> mix_k; Wc[i][o][m] complex, linear
//                                 float idx d lives at region d>>12, off 16384+(d&4095))
//   tw table    : region 0 [32768, 40960)  (twinit -> fwdW)
// inv_fused block bo stages its own Ft to LDS BEFORE overwriting its region.

static constexpr size_t REG = 65536;
static constexpr size_t TW_ABS = 32768;

// ---------------- twiddle table: tw[w*16+k] = e^{-2pi i wk/256} ----------------
__global__ __launch_bounds__(256) void twinit(float* __restrict__ g) {
    int idx = blockIdx.x * 256 + threadIdx.x;   // 0..4095
    int w = idx >> 4, k = idx & 15;
    int r = (w * k) & 255;                      // exact arg reduction
    float s, c;
    sincosf(PI2f * (float)r / 256.0f, &s, &c);
    g[TW_ABS + (size_t)idx * 2]     = c;
    g[TW_ABS + (size_t)idx * 2 + 1] = -s;
}

// ---------------- weights concat: Wc[i][o][m], coalesced both sides ----------------
// float4 units: w1/w2 each 524288 float4. grid MUST be 2048 blocks.
__global__ __launch_bounds__(256) void wcat(const float4* __restrict__ w1,
                                            const float4* __restrict__ w2,
                                            float4* __restrict__ g4) {
    int tid = blockIdx.x * 256 + threadIdx.x;   // 0..524287 (float4 units)
    int io = tid >> 7, rem = tid & 127;
    float4 a = w1[tid];
    float4 b = w2[tid];
    int d1 = io * 256 + rem;                    // Wc float4 idx, m<256 half
    int d2 = d1 + 128;                          // m>=256 half
    g4[(size_t)(d1 >> 10) * 16384 + 4096 + (d1 & 1023)] = a;
    g4[(size_t)(d2 >> 10) * 16384 + 4096 + (d2 & 1023)] = b;
}

// ---------------- stage 1: A[k][h] = sum_w x[h][w] e^{-2pi i k w/256} ----------------
// grid 2048: block = 128 rows of one image. 2 threads per row (w-halves u=0/1),
// 8 chunks x 32 cols, register prefetch of next chunk, twiddles via scalar pipe.
// launch_bounds(256,4): VGPR cap 128 -- accumulators + pf MUST NOT spill.
__global__ __launch_bounds__(256, 4) void fwdW(const float* __restrict__ x,
                                               const float* __restrict__ twg,
                                               float* __restrict__ g) {
    __shared__ float xs[128 * 33];              // 16.9 KB
    const int t = threadIdx.x;
    const int bi = blockIdx.x >> 1, bh = blockIdx.x & 1;
    const float* xim = x + (size_t)bi * 65536 + (size_t)bh * 128 * 256;
    const int r = t & 127, u = t >> 7;          // row-in-tile, col-half
    const int us = __builtin_amdgcn_readfirstlane(u);   // wave-uniform -> SGPR

    float ar[16], ai[16];
#pragma unroll
    for (int k = 0; k < 16; k++) { ar[k] = 0.f; ai[k] = 0.f; }

    // staging map: idx = q*256+t -> row = idx>>3, c4 = (idx&7)*4 (128B/row segments)
    float4 pf[4];
#pragma unroll
    for (int q = 0; q < 4; q++) {
        int idx = q * 256 + t, rr = idx >> 3, c4 = (idx & 7) * 4;
        pf[q] = *(const float4*)(xim + (size_t)rr * 256 + c4);
    }
    for (int cc = 0; cc < 8; cc++) {
        __syncthreads();                        // prev chunk's reads done
#pragma unroll
        for (int q = 0; q < 4; q++) {
            int idx = q * 256 + t, rr = idx >> 3, c4 = (idx & 7) * 4;
            float* d = xs + rr * 33 + c4;
            d[0] = pf[q].x; d[1] = pf[q].y; d[2] = pf[q].z; d[3] = pf[q].w;
        }
        __syncthreads();
        if (cc < 7) {                           // prefetch next chunk into regs
#pragma unroll
            for (int q = 0; q < 4; q++) {
                int idx = q * 256 + t, rr = idx >> 3, c4 = (idx & 7) * 4;
                pf[q] = *(const float4*)(xim + (size_t)rr * 256 + (cc + 1) * 32 + c4);
            }
        }
        const float* xr = xs + r * 33 + us * 16;
        const int w0 = cc * 32 + us * 16;       // fully wave-uniform
#pragma unroll
        for (int w = 0; w < 16; w++) {
            float xv = xr[w];
            const float* tp = twg + (w0 + w) * 32;      // uniform -> s_load
#pragma unroll
            for (int k = 0; k < 16; k++) {
                ar[k] = fmaf(xv, tp[2 * k],     ar[k]);
                ai[k] = fmaf(xv, tp[2 * k + 1], ai[k]);
            }
        }
    }
    // pairwise reduce the two w-halves through LDS (pitch 33 -> spread banks)
    __syncthreads();
    if (u == 1) {
        float* p = xs + r * 33;
#pragma unroll
        for (int k = 0; k < 16; k++) { p[2 * k] = ar[k]; p[2 * k + 1] = ai[k]; }
    }
    __syncthreads();
    if (u == 0) {
        const float* p = xs + r * 33;
        float* Ap = g + (size_t)bi * REG + 8192;
#pragma unroll
        for (int k = 0; k < 16; k++) {
            float vr = ar[k] + p[2 * k];
            float vi = ai[k] + p[2 * k + 1];
            *(float2*)(Ap + ((size_t)k * 256 + bh * 128 + r) * 2) = make_float2(vr, vi);
        }
    }
}

// ---------------- stage 2: X[j][k] = sum_h A[k][h] e^{-2pi i f(j) h/256} ----------------
// 512 threads: one mode per thread (k = t&15, j = t>>4).
__global__ __launch_bounds__(512, 8) void fwdH(float* __restrict__ g) {
    __shared__ float As[16 * 516 + 4];          // [k][h] pad-2 complex, 33 KB
    const int bi = blockIdx.x, t = threadIdx.x;
    const float* Ap = g + (size_t)bi * REG + 8192;
#pragma unroll
    for (int q = 0; q < 4; q++) {
        int f4 = q * 512 + t;                   // float4 id 0..2047
        int k = f4 >> 7, r4 = f4 & 127;
        *(float4*)(As + k * 516 + r4 * 4) = *(const float4*)(Ap + (size_t)f4 * 4);
    }
    __syncthreads();

    const int k = t & 15, j = t >> 4;
    const float* Ak = As + k * 516;
    const int f = (j < 16) ? j : j - 32;
    float s, c;
    sincosf(-PI2f * (float)f / 256.0f, &s, &c);
    float er = 1.f, ei = 0.f, accr = 0.f, acci = 0.f;
    for (int h = 0; h < 256; h++) {
        float a_re = Ak[2 * h], a_im = Ak[2 * h + 1];
        accr = fmaf(a_re, er, fmaf(-a_im, ei, accr));
        acci = fmaf(a_re, ei, fmaf( a_im, er, acci));
        float nr = er * c - ei * s;
        ei = fmaf(er, s, ei * c);
        er = nr;
    }
    float* Xp = g + (size_t)bi * REG + 2048;
    *(float2*)(Xp + ((size_t)j * 16 + k) * 2) = make_float2(accr, acci);
}

// ---------------- stage 3: Ft[b][m][o] = sum_i X[b][i][m] * Wc[i][o][m] ----------------
// wave = (b, o, quarter): lane owns m = qr*128 + l*2 + {0,1}; all loads/stores float4-coalesced
__global__ __launch_bounds__(256) void mix_k(float* __restrict__ g) {
    const int wv = threadIdx.x >> 6, l = threadIdx.x & 63;
    const int W = blockIdx.x * 4 + wv;          // 0..4095
    const int b = W >> 8, o = (W >> 2) & 63, qr = W & 3;
    float acr0 = 0.f, aci0 = 0.f, acr1 = 0.f, aci1 = 0.f;
    for (int i = 0; i < 64; i++) {
        const float4 xv = *(const float4*)(g + (size_t)(b * 64 + i) * REG + 2048 + qr * 256 + l * 4);
        int d0 = (i * 64 + o) * 1024 + qr * 256;    // Wc float idx base
        const float4 wv4 = *(const float4*)(g + (size_t)(d0 >> 12) * REG + 16384 + (d0 & 4095) + l * 4);
        acr0 = fmaf(xv.x, wv4.x, fmaf(-xv.y, wv4.y, acr0));
        aci0 = fmaf(xv.x, wv4.y, fmaf( xv.y, wv4.x, aci0));
        acr1 = fmaf(xv.z, wv4.z, fmaf(-xv.w, wv4.w, acr1));
        aci1 = fmaf(xv.z, wv4.w, fmaf( xv.w, wv4.z, aci1));
    }
    float* Fp = g + (size_t)(b * 64 + o) * REG + qr * 256 + l * 4;
    *(float4*)Fp = make_float4(acr0, aci0, acr1, aci1);
}

// ---------------- inverse: H-iDFT + irfft-W, full-sector coalesced stores ----------------
// block = one bo region. Thread t owns output row h=t.
// Phase 2: 8 chunks x 32 cols (16 lo + 16 mirrored hi, hi stored reversed so it
// is column-ascending). Transpose via 32KB XOR-swizzled LDS tile; float4 stores
// in 64B-aligned segments -> no partial-sector RMW at HBM.
__global__ __launch_bounds__(256, 4) void inv_fused(float* __restrict__ g) {
    __shared__ float Fs[1024];                  // Ft slice, 4 KB
    __shared__ float phS[512];                  // cos/sin(2pi m/256), 2 KB
    __shared__ float T[256 * 32];               // swizzled transpose tile, 32 KB
    const int t = threadIdx.x;
    const int bo = blockIdx.x;
    float* regn = g + (size_t)bo * REG;

    // stage own Ft slice BEFORE any output write
    *(float4*)(Fs + t * 4) = *(const float4*)(regn + (size_t)t * 4);
    float rs, rc;
    sincosf(PI2f * (float)t / 256.0f, &rs, &rc);
    phS[t * 2] = rc; phS[t * 2 + 1] = rs;
    __syncthreads();

    // phase 1: Y[h=t][k] = sum_f Ft[j(f)][k] e^{+2pi i f t/256}, f=-16..15
    float Yr[16], Yi[16];
#pragma unroll
    for (int k = 0; k < 16; k++) { Yr[k] = 0.f; Yi[k] = 0.f; }
    float es, ec;
    sincosf(-PI2f * (float)(t & 15) / 16.0f, &es, &ec); // e^{-2pi i 16 t/256}
    float er = ec, ei = es;
    for (int sdx = 0; sdx < 32; sdx++) {                // f = sdx-16
        int j = (sdx < 16) ? sdx + 16 : sdx - 16;
        const float* fj = Fs + j * 32;
#pragma unroll
        for (int k = 0; k < 16; k++) {
            float fr = fj[2 * k], fi = fj[2 * k + 1];
            Yr[k] = fmaf(fr, er, fmaf(-fi, ei, Yr[k]));
            Yi[k] = fmaf(fr, ei, fmaf( fi, er, Yi[k]));
        }
        float nr = er * rc - ei * rs;
        ei = fmaf(er, rs, ei * rc);
        er = nr;
    }

    // fold irfft weights (k=0: 1, k>=1: 2) and 1/65536
    const float INV = 1.0f / 65536.0f;
    Yr[0] *= INV;
#pragma unroll
    for (int k = 1; k < 16; k++) { Yr[k] *= 2.0f * INV; Yi[k] *= 2.0f * INV; }

    // P(m) = sum_k Yr[k] cos(2pi mk/256), Q(m) = sum_k Yi[k] sin(.)
    auto pq = [&](float c, float s, float& P, float& Q) {
        float c2 = c + c;
        float Cp = c, Cpp = 1.f, Sp = s, Spp = 0.f;
        P = fmaf(Yr[1], c, Yr[0]);
        Q = Yi[1] * s;
#pragma unroll
        for (int k = 2; k < 16; k++) {          // Chebyshev 3-term
            float Cn = fmaf(c2, Cp, -Cpp);
            float Sn = fmaf(c2, Sp, -Spp);
            P = fmaf(Yr[k], Cn, P);
            Q = fmaf(Yi[k], Sn, Q);
            Cpp = Cp; Cp = Cn; Spp = Sp; Sp = Sn;
        }
    };

    // phase 2: per chunk cc, cols lo = [cc*16, cc*16+16) and hi = mirrors
    const int sw = t & 7;                       // swizzle key for own row
    for (int cc = 0; cc < 8; cc++) {
        float lo[16], hi[16];
#pragma unroll
        for (int i = 0; i < 16; i++) {
            int m = cc * 16 + i;
            float P, Q;
            pq(phS[2 * m], phS[2 * m + 1], P, Q);
            lo[i] = P - Q;                      // col m
            hi[i] = P + Q;                      // col 256-m
        }
        if (cc == 0) {                          // m=0 has no mirror; slot carries col 128
            float P, Q;
            pq(-1.0f, 0.0f, P, Q);              // c=-1, s=0 -> Q=0
            hi[0] = P;
        }
        __syncthreads();                        // prev chunk's T reads done
        // T[t][c]: c<16 -> lo[c]; c=16+p -> hi[15-p] (reversed -> ascending cols)
        float* Tr = T + t * 32;
#pragma unroll
        for (int q = 0; q < 4; q++) {
            *(float4*)(Tr + ((q ^ sw) * 4)) =
                make_float4(lo[q * 4], lo[q * 4 + 1], lo[q * 4 + 2], lo[q * 4 + 3]);
        }
#pragma unroll
        for (int q = 0; q < 4; q++) {
            *(float4*)(Tr + (((4 + q) ^ sw) * 4)) =
                make_float4(hi[15 - q * 4], hi[14 - q * 4], hi[13 - q * 4], hi[12 - q * 4]);
        }
        __syncthreads();
        // store-out: row = it*32 + (t>>3), f4 = t&7; 64B segments, float4
        const int rsub = t >> 3, f4 = t & 7;
#pragma unroll
        for (int it = 0; it < 8; it++) {
            int row = it * 32 + rsub;
            float4 v = *(const float4*)(T + row * 32 + ((f4 ^ (row & 7)) * 4));
            if (f4 < 4) {                       // lo block: cols cc*16 + f4*4 ..+3
                *(float4*)(regn + (size_t)row * 256 + cc * 16 + f4 * 4) = v;
            } else {
                int jq = f4 - 4;                // hi block: cols (241-cc*16)+jq*4 ..+3
                if (cc == 0 && jq == 3) {       // cols 253,254,255,128
                    float* rp = regn + (size_t)row * 256;
                    rp[253] = v.x; rp[254] = v.y; rp[255] = v.z; rp[128] = v.w;
                } else {
                    *(float4*)(regn + (size_t)row * 256 + (241 - cc * 16) + jq * 4) = v;
                }
            }
        }
    }
}

extern "C" void kernel_launch(void* const* d_in, const int* in_sizes, int n_in,
                              void* d_out, int out_size, void* d_ws, size_t ws_size,
                              hipStream_t stream) {
    const float* x  = (const float*)d_in[0];
    const float* w1 = (const float*)d_in[1];
    const float* w2 = (const float*)d_in[2];
    float* g = (float*)d_out;
    (void)d_ws; (void)ws_size;

    twinit   <<<16,   256, 0, stream>>>(g);
    wcat     <<<2048, 256, 0, stream>>>((const float4*)w1, (const float4*)w2, (float4*)g);
    fwdW     <<<2048, 256, 0, stream>>>(x, g + TW_ABS, g);
    fwdH     <<<1024, 512, 0, stream>>>(g);
    mix_k    <<<1024, 256, 0, stream>>>(g);
    inv_fused<<<1024, 256, 0, stream>>>(g);
}

// Round 9
// 265.205 us; speedup vs baseline: 2.2804x; 1.0779x over previous
//
#include <hip/hip_runtime.h>
#include <math.h>

#define PI2f 6.28318530717958647692f

// B=16, Ci=Co=64, H=W=256, M1=M2=16. Modes j=0..31, freq f=(j<16)?j:j-32.
//
// ALL scratch lives inside d_out (67,108,864 floats = 1024 regions x 65536).
// Region-relative float offsets:
//   Ft slice bo : [0, 1024)      (mix_k -> inv_fused; 512 modes complex)
//   X  slice bi : [2048, 3072)   (fwd -> mix_k; 512 modes complex)
//   Wc chunk    : [16384, 20480) (prep -> mix_k; Wc[i][o][m] complex, linear
//                                 float idx d lives at region d>>12, off 16384+(d&4095))
//   tw table    : region 0 [32768, 40960)  (prep -> fwd)
// inv_fused block bo stages its own Ft to LDS BEFORE overwriting its region.

static constexpr size_t REG = 65536;
static constexpr size_t TW_ABS = 32768;

// ---------------- prep: weights concat (blocks 0..2047) + twiddle table (2048..2063) ----
__global__ __launch_bounds__(256) void prep(const float4* __restrict__ w1,
                                            const float4* __restrict__ w2,
                                            float4* __restrict__ g4,
                                            float* __restrict__ g) {
    const int b = blockIdx.x;
    if (b < 2048) {                             // wcat: float4 units, 524288 total
        int tid = b * 256 + threadIdx.x;
        int io = tid >> 7, rem = tid & 127;
        float4 a = w1[tid];
        float4 bb = w2[tid];
        int d1 = io * 256 + rem;                // Wc float4 idx, m<256 half
        int d2 = d1 + 128;                      // m>=256 half
        g4[(size_t)(d1 >> 10) * 16384 + 4096 + (d1 & 1023)] = a;
        g4[(size_t)(d2 >> 10) * 16384 + 4096 + (d2 & 1023)] = bb;
    } else {                                    // twinit: tw[w*16+k] = e^{-2pi i wk/256}
        int idx = (b - 2048) * 256 + threadIdx.x;   // 0..4095
        int w = idx >> 4, k = idx & 15;
        int r = (w * k) & 255;                  // exact arg reduction
        float s, c;
        sincosf(PI2f * (float)r / 256.0f, &s, &c);
        g[TW_ABS + (size_t)idx * 2]     = c;
        g[TW_ABS + (size_t)idx * 2 + 1] = -s;
    }
}

// ---------------- forward fused: radix-2 W-DFT then H-DFT ----------------
// grid 1024: block = one (b,i) image, thread t owns row h=t.
// Radix-2 in w: A[k] = sum_{w<128} (x[w] + (-1)^k x[w+128]) e^{-2pi i k w/256}.
// 8 chunks x 16 pairs; xe/xo formed during LDS staging; twiddles via scalar pipe.
// Union LDS: xs[256][35] pair buffer (35.8KB), reused as As[k][h] (pitch 516).
__global__ __launch_bounds__(256, 4) void fwd(const float* __restrict__ x,
                                              const float* __restrict__ twg,
                                              float* __restrict__ g) {
    __shared__ float xs[256 * 35];              // 35.8 KB union buffer
    const int t = threadIdx.x;
    const int bi = blockIdx.x;
    const float* xim = x + (size_t)bi * 65536;

    float ar[16], ai[16];
#pragma unroll
    for (int k = 0; k < 16; k++) { ar[k] = 0.f; ai[k] = 0.f; }

    // staging map (per chunk cc): pair-cols pl = cc*16 .. +16; input cols
    // [cc*16, cc*16+16) (low, q<4) and [cc*16+128, +16) (high, q>=4).
    // float4 id fid = q*256+t (q<4): rr = fid>>2, c4 = (fid&3)*4.
    float4 pf[8];
#pragma unroll
    for (int q = 0; q < 8; q++) {
        int fid = (q & 3) * 256 + t, rr = fid >> 2, c4 = (fid & 3) * 4;
        int cb = (q < 4) ? 0 : 128;
        pf[q] = *(const float4*)(xim + (size_t)rr * 256 + cb + c4);
    }
    for (int cc = 0; cc < 8; cc++) {
        __syncthreads();                        // prev chunk's reads done
#pragma unroll
        for (int q = 0; q < 4; q++) {
            int fid = q * 256 + t, rr = fid >> 2, c4 = (fid & 3) * 4;
            float* d = xs + rr * 35 + c4 * 2;
            float4 lo = pf[q], hi = pf[q + 4];
            d[0] = lo.x + hi.x; d[1] = lo.x - hi.x;
            d[2] = lo.y + hi.y; d[3] = lo.y - hi.y;
            d[4] = lo.z + hi.z; d[5] = lo.z - hi.z;
            d[6] = lo.w + hi.w; d[7] = lo.w - hi.w;
        }
        __syncthreads();
        if (cc < 7) {                           // prefetch next chunk into regs
#pragma unroll
            for (int q = 0; q < 8; q++) {
                int fid = (q & 3) * 256 + t, rr = fid >> 2, c4 = (fid & 3) * 4;
                int cb = (cc + 1) * 16 + ((q < 4) ? 0 : 128);
                pf[q] = *(const float4*)(xim + (size_t)rr * 256 + cb + c4);
            }
        }
        const float* xr = xs + t * 35;
#pragma unroll
        for (int pl = 0; pl < 16; pl++) {
            float xe = xr[pl * 2], xo = xr[pl * 2 + 1];
            const float* tp = twg + (cc * 16 + pl) * 32;    // uniform -> s_load
#pragma unroll
            for (int k = 0; k < 16; k++) {
                float xv = (k & 1) ? xo : xe;
                ar[k] = fmaf(xv, tp[2 * k],     ar[k]);
                ai[k] = fmaf(xv, tp[2 * k + 1], ai[k]);
            }
        }
    }
    // W-part done; reuse xs as As[k][h]: float idx k*516 + h*2
    __syncthreads();
#pragma unroll
    for (int k = 0; k < 16; k++) {
        *(float2*)(xs + k * 516 + t * 2) = make_float2(ar[k], ai[k]);
    }
    __syncthreads();

    // H-DFT: thread (jb = t>>4, k = t&15) computes modes j = jb, jb+16
    const int k = t & 15, jb = t >> 4;
    const float* Ak = xs + k * 516;
    float* Xp = g + (size_t)bi * REG + 2048;
    for (int half = 0; half < 2; half++) {
        int j = jb + half * 16;
        int f = (j < 16) ? j : j - 32;
        float s, c;
        sincosf(-PI2f * (float)f / 256.0f, &s, &c); // ratio e^{-2pi i f/256}
        float er = 1.f, ei = 0.f, accr = 0.f, acci = 0.f;
        for (int h = 0; h < 256; h++) {
            float2 a = *(const float2*)(Ak + 2 * h);
            accr = fmaf(a.x, er, fmaf(-a.y, ei, accr));
            acci = fmaf(a.x, ei, fmaf( a.y, er, acci));
            float nr = er * c - ei * s;
            ei = fmaf(er, s, ei * c);
            er = nr;
        }
        *(float2*)(Xp + ((size_t)j * 16 + k) * 2) = make_float2(accr, acci);
    }
}

// ---------------- stage 3: Ft[b][m][o] = sum_i X[b][i][m] * Wc[i][o][m] ----------------
// wave = (b, o, quarter): lane owns m = qr*128 + l*2 + {0,1}; all loads/stores float4-coalesced
__global__ __launch_bounds__(256) void mix_k(float* __restrict__ g) {
    const int wv = threadIdx.x >> 6, l = threadIdx.x & 63;
    const int W = blockIdx.x * 4 + wv;          // 0..4095
    const int b = W >> 8, o = (W >> 2) & 63, qr = W & 3;
    float acr0 = 0.f, aci0 = 0.f, acr1 = 0.f, aci1 = 0.f;
    for (int i = 0; i < 64; i++) {
        const float4 xv = *(const float4*)(g + (size_t)(b * 64 + i) * REG + 2048 + qr * 256 + l * 4);
        int d0 = (i * 64 + o) * 1024 + qr * 256;    // Wc float idx base
        const float4 wv4 = *(const float4*)(g + (size_t)(d0 >> 12) * REG + 16384 + (d0 & 4095) + l * 4);
        acr0 = fmaf(xv.x, wv4.x, fmaf(-xv.y, wv4.y, acr0));
        aci0 = fmaf(xv.x, wv4.y, fmaf( xv.y, wv4.x, aci0));
        acr1 = fmaf(xv.z, wv4.z, fmaf(-xv.w, wv4.w, acr1));
        aci1 = fmaf(xv.z, wv4.w, fmaf( xv.w, wv4.z, aci1));
    }
    float* Fp = g + (size_t)(b * 64 + o) * REG + qr * 256 + l * 4;
    *(float4*)Fp = make_float4(acr0, aci0, acr1, aci1);
}

// ---------------- inverse: H-iDFT + irfft-W, full-sector coalesced stores ----------------
// block = one bo region. Thread t owns output row h=t.
// Phase 2: 8 chunks x 32 cols (16 lo + 16 mirrored hi, hi stored reversed so it
// is column-ascending). Transpose via 32KB XOR-swizzled LDS tile; float4 stores
// in 64B-aligned segments -> no partial-sector RMW at HBM.
__global__ __launch_bounds__(256, 4) void inv_fused(float* __restrict__ g) {
    __shared__ float Fs[1024];                  // Ft slice, 4 KB
    __shared__ float phS[512];                  // cos/sin(2pi m/256), 2 KB
    __shared__ float T[256 * 32];               // swizzled transpose tile, 32 KB
    const int t = threadIdx.x;
    const int bo = blockIdx.x;
    float* regn = g + (size_t)bo * REG;

    // stage own Ft slice BEFORE any output write
    *(float4*)(Fs + t * 4) = *(const float4*)(regn + (size_t)t * 4);
    float rs, rc;
    sincosf(PI2f * (float)t / 256.0f, &rs, &rc);
    phS[t * 2] = rc; phS[t * 2 + 1] = rs;
    __syncthreads();

    // phase 1: Y[h=t][k] = sum_f Ft[j(f)][k] e^{+2pi i f t/256}, f=-16..15
    float Yr[16], Yi[16];
#pragma unroll
    for (int k = 0; k < 16; k++) { Yr[k] = 0.f; Yi[k] = 0.f; }
    float es, ec;
    sincosf(-PI2f * (float)(t & 15) / 16.0f, &es, &ec); // e^{-2pi i 16 t/256}
    float er = ec, ei = es;
    for (int sdx = 0; sdx < 32; sdx++) {                // f = sdx-16
        int j = (sdx < 16) ? sdx + 16 : sdx - 16;
        const float* fj = Fs + j * 32;
#pragma unroll
        for (int k = 0; k < 16; k++) {
            float fr = fj[2 * k], fi = fj[2 * k + 1];
            Yr[k] = fmaf(fr, er, fmaf(-fi, ei, Yr[k]));
            Yi[k] = fmaf(fr, ei, fmaf( fi, er, Yi[k]));
        }
        float nr = er * rc - ei * rs;
        ei = fmaf(er, rs, ei * rc);
        er = nr;
    }

    // fold irfft weights (k=0: 1, k>=1: 2) and 1/65536
    const float INV = 1.0f / 65536.0f;
    Yr[0] *= INV;
#pragma unroll
    for (int k = 1; k < 16; k++) { Yr[k] *= 2.0f * INV; Yi[k] *= 2.0f * INV; }

    // P(m) = sum_k Yr[k] cos(2pi mk/256), Q(m) = sum_k Yi[k] sin(.)
    auto pq = [&](float c, float s, float& P, float& Q) {
        float c2 = c + c;
        float Cp = c, Cpp = 1.f, Sp = s, Spp = 0.f;
        P = fmaf(Yr[1], c, Yr[0]);
        Q = Yi[1] * s;
#pragma unroll
        for (int k = 2; k < 16; k++) {          // Chebyshev 3-term
            float Cn = fmaf(c2, Cp, -Cpp);
            float Sn = fmaf(c2, Sp, -Spp);
            P = fmaf(Yr[k], Cn, P);
            Q = fmaf(Yi[k], Sn, Q);
            Cpp = Cp; Cp = Cn; Spp = Sp; Sp = Sn;
        }
    };

    // phase 2: per chunk cc, cols lo = [cc*16, cc*16+16) and hi = mirrors
    const int sw = t & 7;                       // swizzle key for own row
    for (int cc = 0; cc < 8; cc++) {
        float lo[16], hi[16];
#pragma unroll
        for (int i = 0; i < 16; i++) {
            int m = cc * 16 + i;
            float P, Q;
            pq(phS[2 * m], phS[2 * m + 1], P, Q);
            lo[i] = P - Q;                      // col m
            hi[i] = P + Q;                      // col 256-m
        }
        if (cc == 0) {                          // m=0 has no mirror; slot carries col 128
            float P, Q;
            pq(-1.0f, 0.0f, P, Q);              // c=-1, s=0 -> Q=0
            hi[0] = P;
        }
        __syncthreads();                        // prev chunk's T reads done
        // T[t][c]: c<16 -> lo[c]; c=16+p -> hi[15-p] (reversed -> ascending cols)
        float* Tr = T + t * 32;
#pragma unroll
        for (int q = 0; q < 4; q++) {
            *(float4*)(Tr + ((q ^ sw) * 4)) =
                make_float4(lo[q * 4], lo[q * 4 + 1], lo[q * 4 + 2], lo[q * 4 + 3]);
        }
#pragma unroll
        for (int q = 0; q < 4; q++) {
            *(float4*)(Tr + (((4 + q) ^ sw) * 4)) =
                make_float4(hi[15 - q * 4], hi[14 - q * 4], hi[13 - q * 4], hi[12 - q * 4]);
        }
        __syncthreads();
        // store-out: row = it*32 + (t>>3), f4 = t&7; 64B segments, float4
        const int rsub = t >> 3, f4 = t & 7;
#pragma unroll
        for (int it = 0; it < 8; it++) {
            int row = it * 32 + rsub;
            float4 v = *(const float4*)(T + row * 32 + ((f4 ^ (row & 7)) * 4));
            if (f4 < 4) {                       // lo block: cols cc*16 + f4*4 ..+3
                *(float4*)(regn + (size_t)row * 256 + cc * 16 + f4 * 4) = v;
            } else {
                int jq = f4 - 4;                // hi block: cols (241-cc*16)+jq*4 ..+3
                if (cc == 0 && jq == 3) {       // cols 253,254,255,128
                    float* rp = regn + (size_t)row * 256;
                    rp[253] = v.x; rp[254] = v.y; rp[255] = v.z; rp[128] = v.w;
                } else {
                    *(float4*)(regn + (size_t)row * 256 + (241 - cc * 16) + jq * 4) = v;
                }
            }
        }
    }
}

extern "C" void kernel_launch(void* const* d_in, const int* in_sizes, int n_in,
                              void* d_out, int out_size, void* d_ws, size_t ws_size,
                              hipStream_t stream) {
    const float* x  = (const float*)d_in[0];
    const float* w1 = (const float*)d_in[1];
    const float* w2 = (const float*)d_in[2];
    float* g = (float*)d_out;
    (void)d_ws; (void)ws_size;

    prep     <<<2064, 256, 0, stream>>>((const float4*)w1, (const float4*)w2, (float4*)g, g);
    fwd      <<<1024, 256, 0, stream>>>(x, g + TW_ABS, g);
    mix_k    <<<1024, 256, 0, stream>>>(g);
    inv_fused<<<1024, 256, 0, stream>>>(g);
}